// Round 3
// baseline (5937.384 us; speedup 1.0000x reference)
//
#include <hip/hip_runtime.h>

#define BS 8
#define HID 64
#define NV 1024
#define NSTEP 64

// out layout (float32, concatenated flat, element offsets):
//   imps  [8][1][1024][64]  at 0
//   preds [8][1][1024][64]  at 524288
//   reprs [8][64][1024][64] at 1048576
#define IMPS_OFF  0
#define PREDS_OFF 524288
#define REPRS_OFF 1048576

// ---------------- init: h ping0 = broadcast h0, preds[t=0] ----------------
__global__ void init_k(const float* __restrict__ h0, const float* __restrict__ Wini,
                       const float* __restrict__ bini,
                       float* __restrict__ hws, float* __restrict__ out){
    int gid = blockIdx.x * blockDim.x + threadIdx.x;
    int nthr = gridDim.x * blockDim.x;
    for (int idx = gid; idx < BS*HID*NV; idx += nthr){
        hws[idx] = h0[idx & (HID*NV - 1)];
    }
    if (gid < NV){
        int v = gid;
        float s = 0.f;
        for (int h = 0; h < HID; ++h) s += h0[h*NV + v] * Wini[h];
        s += bini[0];
        for (int b = 0; b < BS; ++b){
            out[PREDS_OFF + (size_t)b*65536 + (size_t)v*64] = s;  // t=0
        }
    }
}

// ---------------- one recurrence step ----------------
// grid: 256 blocks = 8 batches x 32 node-tiles (32 nodes each), 256 threads
// static LDS ~31 KB.
__global__ __launch_bounds__(256) void step_k(
    int t,
    const float* __restrict__ hin, float* __restrict__ hout,
    const float* __restrict__ graph, const float* __restrict__ ig,
    const float* __restrict__ x, const int* __restrict__ mask,
    const float* __restrict__ Whh, const float* __restrict__ Wih,
    const float* __restrict__ bih, const float* __restrict__ bhh,
    const float* __restrict__ Wini, const float* __restrict__ bini,
    const float* __restrict__ Wo, const float* __restrict__ bo,
    float* out)
{
    __shared__ float xh_s[NV];        // x_hat for all nodes (this batch)
    __shared__ float As[64][36];      // h tile   [h][kk]
    __shared__ float Bs[32][36];      // graph    [w][kk]
    __shared__ float hd2[32*68];      // h_diff   [w][h]
    __shared__ float xgp[8][33];      // x_g partials
    __shared__ float xg_s[32];
    __shared__ float r1[8][33];       // x_hat1_next partials
    __shared__ float r2[8][33];       // x_hat2 partials

    int tid = threadIdx.x;
    int b  = blockIdx.x >> 5;
    int w0 = (blockIdx.x & 31) << 5;

    // ---- phase 0: x_hat[v] = mask ? x : preds[t]  (all 1024 nodes, this b) ----
    {
        size_t base = (size_t)b*65536 + (size_t)t;
        #pragma unroll
        for (int k = 0; k < 4; ++k){
            int v = tid + k*256;
            size_t idx = base + (size_t)v*64;
            int m = mask[idx];
            xh_s[v] = m ? x[idx] : out[PREDS_OFF + idx];
        }
    }
    __syncthreads();

    // ---- phase 1: x_g[w] = sum_v x_hat[v] * ind_graph[w][v] ----
    {
        int w = tid >> 3, p = tid & 7;
        const float* igr = ig + (size_t)(w0 + w) * NV;
        float acc = 0.f;
        #pragma unroll 4
        for (int k = 0; k < 32; ++k){
            int v = k*32 + p*4;
            float4 a = *(const float4*)(igr + v);
            float4 c = *(const float4*)(&xh_s[v]);
            acc += a.x*c.x + a.y*c.y + a.z*c.z + a.w*c.w;
        }
        xgp[p][w] = acc;
    }
    __syncthreads();
    if (tid < 32){
        float s = 0.f;
        #pragma unroll
        for (int p = 0; p < 8; ++p) s += xgp[p][tid];
        xg_s[tid] = s;
    }

    // ---- phase 2: h_diff[h][w] = sum_v h[b][h][v] * graph[w0+w][v] ----
    float acc[4][2];
    #pragma unroll
    for (int i=0;i<4;++i){ acc[i][0]=0.f; acc[i][1]=0.f; }
    int th = tid >> 4;   // 0..15 -> h base th*4
    int tw = tid & 15;   // 0..15 -> w base tw*2
    const float* hb = hin + (size_t)b * HID * NV;
    for (int kc = 0; kc < 32; ++kc){
        int v0 = kc * 32;
        __syncthreads();
        {
            int row = tid >> 3, q = tid & 7;   // row 0..31, q 0..7
            *(float4*)&As[row][q*4]    = *(const float4*)(hb + (size_t)row*NV + v0 + q*4);
            *(float4*)&As[row+32][q*4] = *(const float4*)(hb + (size_t)(row+32)*NV + v0 + q*4);
            *(float4*)&Bs[row][q*4]    = *(const float4*)(graph + (size_t)(w0+row)*NV + v0 + q*4);
        }
        __syncthreads();
        #pragma unroll
        for (int kk = 0; kk < 32; kk += 2){
            float2 av[4]; float2 bv[2];
            #pragma unroll
            for (int i=0;i<4;++i) av[i] = *(const float2*)&As[th*4+i][kk];
            #pragma unroll
            for (int j=0;j<2;++j) bv[j] = *(const float2*)&Bs[tw*2+j][kk];
            #pragma unroll
            for (int i=0;i<4;++i){
                #pragma unroll
                for (int j=0;j<2;++j){
                    acc[i][j] += av[i].x * bv[j].x;
                    acc[i][j] += av[i].y * bv[j].y;
                }
            }
        }
    }
    __syncthreads();
    #pragma unroll
    for (int i=0;i<4;++i)
        #pragma unroll
        for (int j=0;j<2;++j)
            hd2[(tw*2+j)*68 + th*4 + i] = acc[i][j];
    __syncthreads();

    // ---- phase 3: GRU + heads. thread (w = tid&31, hg = tid>>5) does 8 h ----
    {
        int w  = tid & 31, hg = tid >> 5;
        int wg = w0 + w;
        float xg = xg_s[w];
        float4 hdr[16];
        #pragma unroll
        for (int c = 0; c < 16; ++c) hdr[c] = *(const float4*)&hd2[w*68 + c*4];
        float4 hda = *(const float4*)&hd2[w*68 + hg*8];
        float4 hdb = *(const float4*)&hd2[w*68 + hg*8 + 4];
        float p2 = 0.f, p1 = 0.f;
        #pragma unroll
        for (int i = 0; i < 8; ++i){
            int h = hg*8 + i;
            float gr = 0.f, gz = 0.f, gn = 0.f;
            #pragma unroll
            for (int c = 0; c < 16; ++c){
                float4 hv = hdr[c];
                float4 wr = *(const float4*)(Whh + (size_t)(h      )*64 + c*4);
                float4 wz = *(const float4*)(Whh + (size_t)(64 + h )*64 + c*4);
                float4 wn = *(const float4*)(Whh + (size_t)(128 + h)*64 + c*4);
                gr += wr.x*hv.x + wr.y*hv.y + wr.z*hv.z + wr.w*hv.w;
                gz += wz.x*hv.x + wz.y*hv.y + wz.z*hv.z + wz.w*hv.w;
                gn += wn.x*hv.x + wn.y*hv.y + wn.z*hv.z + wn.w*hv.w;
            }
            float ir  = xg * Wih[h]       + bih[h];
            float iz  = xg * Wih[64 + h]  + bih[64 + h];
            float inn = xg * Wih[128 + h] + bih[128 + h];
            float hr = gr + bhh[h];
            float hz = gz + bhh[64 + h];
            float hn = gn + bhh[128 + h];
            float r = 1.f / (1.f + __expf(-(ir + hr)));
            float z = 1.f / (1.f + __expf(-(iz + hz)));
            float n = tanhf(inn + r * hn);
            float hd_v = (i < 4) ? ((i==0)?hda.x:(i==1)?hda.y:(i==2)?hda.z:hda.w)
                                 : ((i==4)?hdb.x:(i==5)?hdb.y:(i==6)?hdb.z:hdb.w);
            float hnew = (1.f - z) * n + z * hd_v;
            hout[(size_t)b*HID*NV + (size_t)h*NV + wg] = hnew;
            out[REPRS_OFF + (((size_t)b*HID + h)*NV + wg)*64 + t] = hnew;
            p2 += Wo[h]   * hnew;
            p1 += Wini[h] * hnew;
        }
        r2[hg][w] = p2;
        r1[hg][w] = p1;
    }
    __syncthreads();
    if (tid < 32){
        int w = tid, wg = w0 + w;
        float s2 = 0.f, s1 = 0.f;
        #pragma unroll
        for (int hg = 0; hg < 8; ++hg){ s2 += r2[hg][w]; s1 += r1[hg][w]; }
        s2 += bo[0];
        s1 += bini[0];
        size_t base = (size_t)b*65536 + (size_t)wg*64;
        out[IMPS_OFF + base + t] = s2;           // imps[t] = W_out.h_new + b_out
        if (t < NSTEP - 1){
            out[PREDS_OFF + base + (t+1)] = s1;  // preds[t+1] = W_init.h_new + b_init
        }
    }
}

extern "C" void kernel_launch(void* const* d_in, const int* in_sizes, int n_in,
                              void* d_out, int out_size, void* d_ws, size_t ws_size,
                              hipStream_t stream) {
    const float* x     = (const float*)d_in[0];
    const int*   mask  = (const int*)  d_in[1];
    const float* graph = (const float*)d_in[2];
    const float* ind   = (const float*)d_in[3];
    const float* h0    = (const float*)d_in[4];
    const float* Wini  = (const float*)d_in[5];
    const float* bini  = (const float*)d_in[6];
    const float* Wo    = (const float*)d_in[7];
    const float* bo    = (const float*)d_in[8];
    const float* Wih   = (const float*)d_in[9];
    const float* Whh   = (const float*)d_in[10];
    const float* bih   = (const float*)d_in[11];
    const float* bhh   = (const float*)d_in[12];
    float* out = (float*)d_out;

    // workspace: f32 h ping-pong, 2 x 2 MB
    float* hws = (float*)d_ws;

    init_k<<<dim3(256), dim3(256), 0, stream>>>(h0, Wini, bini, hws, out);
    for (int t = 0; t < NSTEP; ++t){
        const float* hin  = hws + (size_t)(t & 1) * (BS*HID*NV);
        float*       hout = hws + (size_t)((t+1) & 1) * (BS*HID*NV);
        step_k<<<dim3(256), dim3(256), 0, stream>>>(
            t, hin, hout, graph, ind, x, mask,
            Whh, Wih, bih, bhh, Wini, bini, Wo, bo, out);
    }
}

// Round 5
// 1219.817 us; speedup vs baseline: 4.8674x; 4.8674x over previous
//
#include <hip/hip_runtime.h>
#include <hip/hip_bf16.h>

#define BS 8
#define HID 64
#define NV 1024
#define NSTEP 64

// out layout (float32, concatenated flat, element offsets):
//   imps  [8][1][1024][64]  at 0
//   preds [8][1][1024][64]  at 524288
//   reprs [8][64][1024][64] at 1048576
#define IMPS_OFF  0
#define PREDS_OFF 524288
#define REPRS_OFF 1048576

typedef unsigned short u16;
typedef __attribute__((ext_vector_type(8))) short bf8;   // 8 bf16 = one MFMA operand
typedef __attribute__((ext_vector_type(4))) float f4;    // 4 f32 accumulator

__device__ __forceinline__ u16 f2bf(float f){
    __hip_bfloat16 h = __float2bfloat16(f);
    return *reinterpret_cast<u16*>(&h);
}
// 8 packed bf16 (uint4) -> 8 f32
__device__ __forceinline__ void cv8(uint4 u, float* o){
    o[0] = __uint_as_float(u.x << 16); o[1] = __uint_as_float(u.x & 0xffff0000u);
    o[2] = __uint_as_float(u.y << 16); o[3] = __uint_as_float(u.y & 0xffff0000u);
    o[4] = __uint_as_float(u.z << 16); o[5] = __uint_as_float(u.z & 0xffff0000u);
    o[6] = __uint_as_float(u.w << 16); o[7] = __uint_as_float(u.w & 0xffff0000u);
}

// ---------------- convert f32 inputs -> bf16 working copies ----------------
__global__ void conv_k(const float* __restrict__ g, const float* __restrict__ ig,
                       const float* __restrict__ whh, const float* __restrict__ h0,
                       u16* __restrict__ g_b, u16* __restrict__ ig_b,
                       u16* __restrict__ whh_b, u16* __restrict__ hws){
    int gid = blockIdx.x * blockDim.x + threadIdx.x;
    int nt = gridDim.x * blockDim.x;
    for (int i = gid; i < NV*NV; i += nt){ g_b[i] = f2bf(g[i]); ig_b[i] = f2bf(ig[i]); }
    for (int i = gid; i < 192*64; i += nt) whh_b[i] = f2bf(whh[i]);
    for (int i = gid; i < BS*HID*NV; i += nt) hws[i] = f2bf(h0[i & (HID*NV - 1)]);
}

// ---------------- preds[t=0] = W_init . h0 + b_init (f32) ----------------
__global__ void init_k(const float* __restrict__ h0, const float* __restrict__ Wini,
                       const float* __restrict__ bini, float* __restrict__ out){
    int v = blockIdx.x * blockDim.x + threadIdx.x;
    if (v < NV){
        float s = 0.f;
        for (int h = 0; h < HID; ++h) s += h0[h*NV + v] * Wini[h];
        s += bini[0];
        for (int b = 0; b < BS; ++b)
            out[PREDS_OFF + (size_t)b*65536 + (size_t)v*64] = s;
    }
}

// ---------------- one recurrence step (MFMA) ----------------
// grid: 256 blocks = 8 batches x 32 node-tiles (32 nodes), 256 threads (4 waves)
__global__ __launch_bounds__(256) void step_k(
    int t,
    const u16* __restrict__ hin, u16* __restrict__ hout,
    const u16* __restrict__ g_b, const u16* __restrict__ ig_b,
    const u16* __restrict__ whh_b,
    const float* __restrict__ x, const int* __restrict__ mask,
    const float* __restrict__ Wih, const float* __restrict__ bih,
    const float* __restrict__ bhh,
    const float* __restrict__ Wini, const float* __restrict__ bini,
    const float* __restrict__ Wo, const float* __restrict__ bo,
    float* out, float* __restrict__ rtmp, int staged)
{
    __shared__ float xh_s[NV];                          // 4 KB
    __shared__ __align__(16) u16 A_s[2][64][72];        // 18 KB  h tile, dbuf, padded
    __shared__ __align__(16) u16 G_s[2][32][72];        // 9.2 KB graph tile
    __shared__ __align__(16) float hdf[32][68];         // 8.7 KB h_diff f32 [w][h]
    __shared__ __align__(16) u16 hdb[32][72];           // 4.6 KB h_diff bf16 [w][h]
    __shared__ __align__(16) float hnf[32][68];         // 8.7 KB h_new f32 [w][h]
    __shared__ float xgp[8][33];
    __shared__ float xg_s[32];
    __shared__ float r1[8][33], r2[8][33];

    const int tid  = threadIdx.x;
    const int b    = blockIdx.x >> 5;
    const int w0   = (blockIdx.x & 31) << 5;
    const int lane = tid & 63;
    const int wv   = tid >> 6;       // wave id 0..3
    const int m16  = lane & 15;
    const int quad = lane >> 4;

    // ---- phase 0: x_hat[v] = mask ? x : preds[t] ----
    {
        size_t base = (size_t)b*65536 + (size_t)t;
        #pragma unroll
        for (int k = 0; k < 4; ++k){
            int v = tid + k*256;
            size_t idx = base + (size_t)v*64;
            xh_s[v] = mask[idx] ? x[idx] : out[PREDS_OFF + idx];
        }
    }
    __syncthreads();

    // ---- phase 1: x_g[w] = sum_v x_hat[v] * ind_graph[w][v] (VALU, bf16 ig) ----
    {
        int w = tid >> 3, p = tid & 7;
        const u16* igr = ig_b + (size_t)(w0 + w) * NV;
        float acc = 0.f;
        for (int k = 0; k < 16; ++k){
            int v = p*8 + k*64;
            uint4 u = *(const uint4*)(igr + v);
            float gg[8]; cv8(u, gg);
            #pragma unroll
            for (int j = 0; j < 8; ++j) acc += gg[j] * xh_s[v + j];
        }
        xgp[p][w] = acc;
    }
    __syncthreads();
    if (tid < 32){
        float s = 0.f;
        #pragma unroll
        for (int p = 0; p < 8; ++p) s += xgp[p][tid];
        xg_s[tid] = s;   // consumed after several later barriers
    }

    // ---- phase 2: h_diff = h . graph^T via MFMA, K=1024, BK=64, dbuf LDS ----
    const u16* hb = hin + (size_t)b * HID * NV;
    const int arow = tid >> 3;       // 0..31
    const int acol = tid & 7;        // 0..7 (16B group)
    uint4 pa0, pa1, pg;
    pa0 = *(const uint4*)(hb + (size_t)arow*NV + acol*8);
    pa1 = *(const uint4*)(hb + (size_t)(arow+32)*NV + acol*8);
    pg  = *(const uint4*)(g_b + (size_t)(w0 + arow)*NV + acol*8);
    *(uint4*)&A_s[0][arow][acol*8]      = pa0;
    *(uint4*)&A_s[0][arow+32][acol*8]   = pa1;
    *(uint4*)&G_s[0][arow][acol*8]      = pg;
    __syncthreads();

    f4 accA0 = {0.f,0.f,0.f,0.f}, accA1 = {0.f,0.f,0.f,0.f};
    const int mrow = wv*16 + m16;    // A (h) row for this wave's fragment
    for (int c = 0; c < 16; ++c){
        int cur = c & 1, nxt = cur ^ 1;
        if (c < 15){
            int v0 = (c+1)*64;
            pa0 = *(const uint4*)(hb + (size_t)arow*NV + v0 + acol*8);
            pa1 = *(const uint4*)(hb + (size_t)(arow+32)*NV + v0 + acol*8);
            pg  = *(const uint4*)(g_b + (size_t)(w0+arow)*NV + v0 + acol*8);
        }
        #pragma unroll
        for (int kk = 0; kk < 2; ++kk){
            bf8 af  = *(const bf8*)&A_s[cur][mrow][kk*32 + quad*8];
            bf8 bf0 = *(const bf8*)&G_s[cur][m16][kk*32 + quad*8];
            bf8 bf1 = *(const bf8*)&G_s[cur][16 + m16][kk*32 + quad*8];
            accA0 = __builtin_amdgcn_mfma_f32_16x16x32_bf16(af, bf0, accA0, 0, 0, 0);
            accA1 = __builtin_amdgcn_mfma_f32_16x16x32_bf16(af, bf1, accA1, 0, 0, 0);
        }
        if (c < 15){
            *(uint4*)&A_s[nxt][arow][acol*8]    = pa0;
            *(uint4*)&A_s[nxt][arow+32][acol*8] = pa1;
            *(uint4*)&G_s[nxt][arow][acol*8]    = pg;
        }
        __syncthreads();
    }

    // C/D layout: col = lane&15 (w within tile), row = quad*4 + reg (h in strip)
    {
        int h4 = wv*16 + quad*4;
        #pragma unroll
        for (int wt = 0; wt < 2; ++wt){
            int w = wt*16 + m16;
            f4 a = wt ? accA1 : accA0;
            *(f4*)&hdf[w][h4] = a;
            ushort4 pk;
            pk.x = f2bf(a[0]); pk.y = f2bf(a[1]); pk.z = f2bf(a[2]); pk.w = f2bf(a[3]);
            *(ushort4*)&hdb[w][h4] = pk;
        }
    }
    __syncthreads();

    // ---- phase 3: gates gh = W_hh . h_diff via MFMA (K=64) ----
    // wave wv handles g rows {wv*16.., 64+wv*16.., 128+wv*16..} = r/z/n gates
    // for hidden units h in [16*wv, 16*wv+16)
    f4 accG[3][2];
    #pragma unroll
    for (int i = 0; i < 3; ++i){ accG[i][0] = (f4){0,0,0,0}; accG[i][1] = (f4){0,0,0,0}; }
    #pragma unroll
    for (int gi3 = 0; gi3 < 3; ++gi3){
        int g16 = gi3*64 + wv*16;
        #pragma unroll
        for (int ks = 0; ks < 2; ++ks){
            bf8 af = *(const bf8*)(whh_b + (size_t)(g16 + m16)*64 + ks*32 + quad*8);
            #pragma unroll
            for (int wt = 0; wt < 2; ++wt){
                bf8 bfr = *(const bf8*)&hdb[wt*16 + m16][ks*32 + quad*8];
                accG[gi3][wt] = __builtin_amdgcn_mfma_f32_16x16x32_bf16(af, bfr, accG[gi3][wt], 0, 0, 0);
            }
        }
    }

    // ---- phase 4: GRU elementwise ----
    {
        int h4 = wv*16 + quad*4;
        #pragma unroll
        for (int wt = 0; wt < 2; ++wt){
            int w = wt*16 + m16;
            float xg = xg_s[w];
            f4 hd4 = *(const f4*)&hdf[w][h4];
            f4 hn4;
            #pragma unroll
            for (int r = 0; r < 4; ++r){
                int h = h4 + r;
                float ir  = xg * Wih[h]       + bih[h];
                float iz  = xg * Wih[64 + h]  + bih[64 + h];
                float inn = xg * Wih[128 + h] + bih[128 + h];
                float hr  = accG[0][wt][r] + bhh[h];
                float hz  = accG[1][wt][r] + bhh[64 + h];
                float hnn = accG[2][wt][r] + bhh[128 + h];
                float rg = 1.f / (1.f + __expf(-(ir + hr)));
                float zg = 1.f / (1.f + __expf(-(iz + hz)));
                float ng = tanhf(inn + rg * hnn);
                hn4[r] = (1.f - zg) * ng + zg * hd4[r];
            }
            *(f4*)&hnf[w][h4] = hn4;
        }
    }
    __syncthreads();

    // ---- phase 5: outputs ----
    {   // head partial dots over h (8 groups of 8)
        int w2 = tid & 31, hg = tid >> 5;
        float s1 = 0.f, s2 = 0.f;
        #pragma unroll
        for (int j = 0; j < 8; ++j){
            float hv = hnf[w2][hg*8 + j];
            s1 += Wini[hg*8 + j] * hv;
            s2 += Wo[hg*8 + j]   * hv;
        }
        r1[hg][w2] = s1; r2[hg][w2] = s2;
    }
    {   // h_out (bf16, coalesced) + reprs
        int h = tid >> 2, wq = tid & 3;
        float vals[8];
        #pragma unroll
        for (int j = 0; j < 8; ++j) vals[j] = hnf[wq*8 + j][h];
        u16 pk[8];
        #pragma unroll
        for (int j = 0; j < 8; ++j) pk[j] = f2bf(vals[j]);
        // FIX (round 4 bug): include batch offset b*HID*NV in hout address
        *(uint4*)(hout + (size_t)b*HID*NV + (size_t)h*NV + w0 + wq*8) = *(uint4*)pk;
        if (staged){
            float* rp = rtmp + (((size_t)t*BS + b)*HID + h)*NV + w0 + wq*8;
            float4 a = {vals[0], vals[1], vals[2], vals[3]};
            float4 c = {vals[4], vals[5], vals[6], vals[7]};
            *(float4*)rp       = a;
            *(float4*)(rp + 4) = c;
        } else {
            size_t rb = REPRS_OFF + (((size_t)b*HID + h)*NV + w0 + wq*8)*64 + t;
            #pragma unroll
            for (int j = 0; j < 8; ++j) out[rb + (size_t)j*64] = vals[j];
        }
    }
    __syncthreads();
    if (tid < 32){
        int w = tid, wg = w0 + w;
        float s1 = 0.f, s2 = 0.f;
        #pragma unroll
        for (int hg = 0; hg < 8; ++hg){ s1 += r1[hg][w]; s2 += r2[hg][w]; }
        s1 += bini[0]; s2 += bo[0];
        size_t base = (size_t)b*65536 + (size_t)wg*64;
        out[IMPS_OFF + base + t] = s2;                 // imps[t] = W_out.h_new + b_out
        if (t < NSTEP - 1)
            out[PREDS_OFF + base + t + 1] = s1;        // preds[t+1]
    }
}

// ---------------- reprs staging [t][b][h][v] -> out [b][h][v][t] ----------------
__global__ void transpose_k(const float* __restrict__ rtmp, float* __restrict__ out){
    __shared__ float tile[64][65];
    int bh = blockIdx.x >> 4;          // 0..511 = b*64 + h
    int b  = bh >> 6, h = bh & 63;
    int v0 = (blockIdx.x & 15) << 6;
    int tid = threadIdx.x;
    int q = tid >> 6, l = tid & 63;
    #pragma unroll 4
    for (int r = 0; r < 16; ++r){
        int tt = r*4 + q;
        tile[tt][l] = rtmp[(((size_t)tt*BS + b)*HID + h)*NV + v0 + l];
    }
    __syncthreads();
    #pragma unroll 4
    for (int r = 0; r < 16; ++r){
        int vv = r*4 + q;
        out[REPRS_OFF + (((size_t)b*HID + h)*NV + v0 + vv)*64 + l] = tile[l][vv];
    }
}

extern "C" void kernel_launch(void* const* d_in, const int* in_sizes, int n_in,
                              void* d_out, int out_size, void* d_ws, size_t ws_size,
                              hipStream_t stream) {
    const float* x     = (const float*)d_in[0];
    const int*   mask  = (const int*)  d_in[1];
    const float* graph = (const float*)d_in[2];
    const float* ind   = (const float*)d_in[3];
    const float* h0    = (const float*)d_in[4];
    const float* Wini  = (const float*)d_in[5];
    const float* bini  = (const float*)d_in[6];
    const float* Wo    = (const float*)d_in[7];
    const float* bo    = (const float*)d_in[8];
    const float* Wih   = (const float*)d_in[9];
    const float* Whh   = (const float*)d_in[10];
    const float* bih   = (const float*)d_in[11];
    const float* bhh   = (const float*)d_in[12];
    float* out = (float*)d_out;

    char* ws = (char*)d_ws;
    u16*   hws   = (u16*)(ws);                         // 2 x 1 MB bf16 h ping-pong
    u16*   g_b   = (u16*)(ws + ((size_t)2<<20));       // 2 MB
    u16*   ig_b  = (u16*)(ws + ((size_t)4<<20));       // 2 MB
    u16*   whh_b = (u16*)(ws + ((size_t)6<<20));       // 24 KB
    float* rtmp  = (float*)(ws + ((size_t)8<<20));     // 128 MB reprs staging
    size_t need_staged = ((size_t)8<<20) + (size_t)NSTEP*BS*HID*NV*4;
    int staged = (ws_size >= need_staged) ? 1 : 0;

    conv_k<<<dim3(2048), dim3(256), 0, stream>>>(graph, ind, Whh, h0,
                                                 g_b, ig_b, whh_b, hws);
    init_k<<<dim3(4), dim3(256), 0, stream>>>(h0, Wini, bini, out);
    for (int t = 0; t < NSTEP; ++t){
        const u16* hin  = hws + (size_t)(t & 1) * (BS*HID*NV);
        u16*       hout = hws + (size_t)((t+1) & 1) * (BS*HID*NV);
        step_k<<<dim3(256), dim3(256), 0, stream>>>(
            t, hin, hout, g_b, ig_b, whh_b, x, mask,
            Wih, bih, bhh, Wini, bini, Wo, bo, out, rtmp, staged);
    }
    if (staged) transpose_k<<<dim3(8192), dim3(256), 0, stream>>>(rtmp, out);
}